// Round 1
// baseline (557.128 us; speedup 1.0000x reference)
//
#include <hip/hip_runtime.h>

typedef __bf16 bf16;
typedef __bf16 b16x8 __attribute__((ext_vector_type(8)));
typedef __bf16 b16x4 __attribute__((ext_vector_type(4)));
typedef float f32x4 __attribute__((ext_vector_type(4)));

#define TB 256
#define LDA 136          // LDS A-tile row stride (bf16), 272B => 2-way bank alias (free)
#define NB 1024
#define NK 24
#define NE 552
#define NH 128
#define BEcnt (NB*NE)    // 565248
#define BNODE (NB*NK)    // 24576
#define EPS 1e-5f

// ---- workspace layout ----
// float-indexed stats region (zeroed each launch):
#define S_BN1 0          // [256] sum/sumsq
#define S_BN3 256        // [256]
#define S_B2  512        // [32][256] bucketed
#define S_B4  8704       // [32][256]
#define S_SC2 16896      // [256] scale2/shift2 (written by k4a block 0)
#define STATS_BYTES (17152*4)
// byte offsets (all 16B aligned)
#define OFF_H1  68608ull
#define OFF_H3  (OFF_H1 + 6291456ull)
#define OFF_Y2R (OFF_H3 + 6291456ull)
#define OFF_Y2S (OFF_Y2R + 12582912ull)
#define OFF_Y4R (OFF_Y2S + 12582912ull)
#define OFF_Y4S (OFF_Y4R + 12582912ull)
#define OFF_Z4  (OFF_Y4S + 12582912ull)
#define OFF_H2  (OFF_Z4 + 12582912ull)   // h2 bf16: 144,703,488 B ; total ~220 MB

__device__ __forceinline__ float elu(float x){ return x > 0.f ? x : __expf(x) - 1.f; }

// B-fragment: lane l holds W[n0 + (l&15)][k0 + (l>>4)*8 + j], j=0..7 (W is [out][in] row-major fp32)
__device__ __forceinline__ b16x8 load_bfrag(const float* W, int ldw, int row, int kcol){
  const float* p = W + row*ldw + kcol;
  f32x4 v0 = *(const f32x4*)p;
  f32x4 v1 = *(const f32x4*)(p+4);
  b16x8 r;
  r[0]=(bf16)v0[0]; r[1]=(bf16)v0[1]; r[2]=(bf16)v0[2]; r[3]=(bf16)v0[3];
  r[4]=(bf16)v1[0]; r[5]=(bf16)v1[1]; r[6]=(bf16)v1[2]; r[7]=(bf16)v1[3];
  return r;
}

__device__ __forceinline__ void load_bfrags(const float* W, int ldw, int k0, b16x8 bfr[4][2], int lane, int w){
  int n = lane & 15, q = lane >> 4;
  #pragma unroll
  for (int kb=0; kb<4; ++kb)
    #pragma unroll
    for (int t=0; t<2; ++t)
      bfr[kb][t] = load_bfrag(W, ldw, (w*2+t)*16 + n, k0 + kb*32 + q*8);
}

// A-frag: lane l holds As[mt*16 + (l&15)][kb*32 + (l>>4)*8 + j]; C/D: row=(l>>4)*4+i, col=l&15
__device__ __forceinline__ void gemm_regB(const bf16* As, const b16x8 bfr[4][2], f32x4 acc[6][2], int lane){
  int m = lane & 15, q = lane >> 4;
  #pragma unroll
  for (int kb=0; kb<4; ++kb){
    int ka = kb*32 + q*8;
    b16x8 a[6];
    #pragma unroll
    for (int mt=0; mt<6; ++mt)
      a[mt] = *(const b16x8*)(As + (mt*16+m)*LDA + ka);
    #pragma unroll
    for (int mt=0; mt<6; ++mt)
      #pragma unroll
      for (int t=0; t<2; ++t)
        acc[mt][t] = __builtin_amdgcn_mfma_f32_16x16x32_bf16(a[mt], bfr[kb][t], acc[mt][t], 0,0,0);
  }
}

__device__ __forceinline__ void zero_acc(f32x4 acc[6][2]){
  #pragma unroll
  for (int mt=0; mt<6; ++mt)
    #pragma unroll
    for (int t=0; t<2; ++t){ acc[mt][t][0]=0.f; acc[mt][t][1]=0.f; acc[mt][t][2]=0.f; acc[mt][t][3]=0.f; }
}

__device__ __forceinline__ void epilogue_to_lds(const f32x4 acc[6][2], const float* bias, bf16* As,
                                                int lane, int w, int validRows){
  int q = lane >> 4, n = lane & 15;
  #pragma unroll
  for (int mt=0; mt<6; ++mt)
    #pragma unroll
    for (int t=0; t<2; ++t){
      int col = (w*2+t)*16 + n;
      float bc = bias[col];
      #pragma unroll
      for (int i=0; i<4; ++i){
        int row = mt*16 + q*4 + i;
        float v = (row < validRows) ? elu(acc[mt][t][i] + bc) : 0.f;
        As[row*LDA + col] = (bf16)v;
      }
    }
}

__device__ __forceinline__ void write_acc_f32(const f32x4 acc[6][2], float* out, int lane, int w){
  int q = lane >> 4, n = lane & 15;
  #pragma unroll
  for (int mt=0; mt<6; ++mt)
    #pragma unroll
    for (int t=0; t<2; ++t){
      int col = (w*2+t)*16 + n;
      #pragma unroll
      for (int i=0; i<4; ++i)
        out[(mt*16 + q*4 + i)*NH + col] = acc[mt][t][i];
    }
}

__device__ __forceinline__ void store_and_stats(const bf16* As, bf16* g_out, float* statsDst,
                                                int tid, int validRows){
  for (int i = tid; i < validRows*16; i += TB){
    int row = i >> 4, c8 = (i & 15) << 3;
    *(b16x8*)(g_out + (size_t)row*NH + c8) = *(const b16x8*)(As + row*LDA + c8);
  }
  int c = tid & 127, half = tid >> 7;
  float s = 0.f, s2 = 0.f;
  for (int row = half; row < validRows; row += 2){
    float v = (float)As[row*LDA + c];
    s += v; s2 += v*v;
  }
  atomicAdd(&statsDst[c], s);
  atomicAdd(&statsDst[128+c], s2);
}

// ---- K1: MLP1 (6->128 VALU, 128->128 MFMA), store pre-BN h1 (bf16) + BN1 stats ----
__global__ __launch_bounds__(TB) void k1_mlp1(const float* __restrict__ in,
    const float* __restrict__ w1, const float* __restrict__ b1,
    const float* __restrict__ w2, const float* __restrict__ b2,
    bf16* __restrict__ h1, float* __restrict__ bn1){
  __shared__ alignas(16) bf16 As[96*LDA];
  __shared__ float w1s[128*6];
  __shared__ float b1s[128], b2s[128];
  __shared__ float ins[96*6];
  int tid = threadIdx.x;
  int row0 = blockIdx.x * 96;
  for (int i=tid; i<768; i+=TB) w1s[i] = w1[i];
  if (tid < 128){ b1s[tid]=b1[tid]; b2s[tid]=b2[tid]; }
  for (int i=tid; i<576; i+=TB) ins[i] = in[row0*6 + i];
  __syncthreads();
  for (int i=tid; i<96*32; i+=TB){
    int row = i >> 5, c4 = (i & 31) << 2;
    float x0=ins[row*6+0], x1=ins[row*6+1], x2=ins[row*6+2],
          x3=ins[row*6+3], x4=ins[row*6+4], x5=ins[row*6+5];
    #pragma unroll
    for (int j=0; j<4; ++j){
      int c = c4 + j;
      const float* wr = w1s + c*6;
      float s = b1s[c] + wr[0]*x0 + wr[1]*x1 + wr[2]*x2 + wr[3]*x3 + wr[4]*x4 + wr[5]*x5;
      As[row*LDA + c] = (bf16)elu(s);
    }
  }
  int lane = tid & 63, w = tid >> 6;
  b16x8 bfr[4][2];
  load_bfrags(w2, 128, 0, bfr, lane, w);
  __syncthreads();
  f32x4 acc[6][2]; zero_acc(acc);
  gemm_regB(As, bfr, acc, lane);
  __syncthreads();
  epilogue_to_lds(acc, b2s, As, lane, w, 96);
  __syncthreads();
  store_and_stats(As, h1 + (size_t)row0*NH, bn1, tid, 96);
}

// ---- K2/K4b: fold BN affine, compute yr = W[:, :128]@x, ys = W[:,128:256]@x per node ----
__global__ __launch_bounds__(TB) void k_project(const bf16* __restrict__ hin,
    const float* __restrict__ stats, float cnt,
    const float* __restrict__ g, const float* __restrict__ be,
    const float* __restrict__ Wp, int ldw,
    float* __restrict__ yr, float* __restrict__ ys){
  __shared__ alignas(16) bf16 As[96*LDA];
  __shared__ float scl[128], shf[128];
  int tid = threadIdx.x;
  int row0 = blockIdx.x * 96;
  if (tid < 128){
    float mean = stats[tid] / cnt;
    float var  = stats[128+tid] / cnt - mean*mean;
    float rs = rsqrtf(var + EPS);
    float sc = g[tid] * rs;
    scl[tid] = sc; shf[tid] = be[tid] - mean*sc;
  }
  __syncthreads();
  for (int i=tid; i<96*16; i+=TB){
    int row = i >> 4, c8 = (i & 15) << 3;
    b16x8 v = *(const b16x8*)(hin + (size_t)(row0+row)*NH + c8);
    b16x8 o;
    #pragma unroll
    for (int j=0; j<8; ++j) o[j] = (bf16)(scl[c8+j]*(float)v[j] + shf[c8+j]);
    *(b16x8*)(As + row*LDA + c8) = o;
  }
  int lane = tid & 63, w = tid >> 6;
  b16x8 bfr[4][2];
  load_bfrags(Wp, ldw, 0, bfr, lane, w);
  __syncthreads();
  f32x4 acc[6][2]; zero_acc(acc);
  gemm_regB(As, bfr, acc, lane);
  write_acc_f32(acc, yr + (size_t)row0*NH, lane, w);
  load_bfrags(Wp, ldw, 128, bfr, lane, w);
  zero_acc(acc);
  gemm_regB(As, bfr, acc, lane);
  write_acc_f32(acc, ys + (size_t)row0*NH, lane, w);
}

// ---- K3: per-edge MLP2: gather yr[recv]+ys[send]+b, ELU, 128x128 MFMA, +b, ELU -> h2 + BN2 stats ----
__global__ __launch_bounds__(TB) void k3_edge1(const float* __restrict__ y2r, const float* __restrict__ y2s,
    const float* __restrict__ b21, const float* __restrict__ w22, const float* __restrict__ b22,
    bf16* __restrict__ h2, float* __restrict__ bn2buck){
  __shared__ alignas(16) bf16 As[96*LDA];
  __shared__ float b1s[128], b2s[128];
  int tid = threadIdx.x;
  int b = blockIdx.x / 6, tile = blockIdx.x % 6;
  int e0 = tile * 92;
  if (tid < 128){ b1s[tid]=b21[tid]; b2s[tid]=b22[tid]; }
  __syncthreads();
  const float* yrb = y2r + (size_t)b*NK*NH;
  const float* ysb = y2s + (size_t)b*NK*NH;
  for (int i=tid; i<96*32; i+=TB){
    int row = i >> 5, c4 = (i & 31) << 2;
    b16x4 o;
    if (row < 92){
      int e = e0 + row;
      int r = e / 23;
      int j = e - r*23;
      int s = j + (j >= r);
      f32x4 vr = *(const f32x4*)(yrb + r*NH + c4);
      f32x4 vs = *(const f32x4*)(ysb + s*NH + c4);
      #pragma unroll
      for (int k=0; k<4; ++k) o[k] = (bf16)elu(vr[k] + vs[k] + b1s[c4+k]);
    } else {
      #pragma unroll
      for (int k=0; k<4; ++k) o[k] = (bf16)0.f;
    }
    *(b16x4*)(As + row*LDA + c4) = o;
  }
  int lane = tid & 63, w = tid >> 6;
  b16x8 bfr[4][2];
  load_bfrags(w22, 128, 0, bfr, lane, w);
  __syncthreads();
  f32x4 acc[6][2]; zero_acc(acc);
  gemm_regB(As, bfr, acc, lane);
  __syncthreads();
  epilogue_to_lds(acc, b2s, As, lane, w, 92);
  __syncthreads();
  store_and_stats(As, h2 + (size_t)(b*NE + e0)*NH, bn2buck + (blockIdx.x & 31)*256, tid, 92);
}

// ---- K4a: finalize BN2, edge2node(h2), MLP3 (two MFMA layers) -> h3 + BN3 stats; block0 exports BN2 affine ----
__global__ __launch_bounds__(TB) void k4a_mlp3(const bf16* __restrict__ h2,
    const float* __restrict__ bn2buck, const float* __restrict__ g2, const float* __restrict__ be2,
    const float* __restrict__ w31, const float* __restrict__ b31,
    const float* __restrict__ w32, const float* __restrict__ b32,
    bf16* __restrict__ h3, float* __restrict__ bn3, float* __restrict__ sc2out){
  __shared__ alignas(16) bf16 As[96*LDA];
  __shared__ float scl[128], shf[128], b1s[128], b2s[128];
  __shared__ float sred[256];
  int tid = threadIdx.x;
  int row0 = blockIdx.x * 96;
  {
    int c = tid & 127, part = tid >> 7;
    float s = 0.f;
    for (int i=0; i<32; ++i) s += bn2buck[i*256 + part*128 + c];
    sred[tid] = s;
  }
  if (tid < 128){ b1s[tid]=b31[tid]; b2s[tid]=b32[tid]; }
  __syncthreads();
  if (tid < 128){
    float mean = sred[tid] / (float)BEcnt;
    float var  = sred[128+tid] / (float)BEcnt - mean*mean;
    float rs = rsqrtf(var + EPS);
    float sc = g2[tid] * rs;
    float sh = be2[tid] - mean*sc;
    scl[tid] = sc; shf[tid] = sh;
    if (blockIdx.x == 0){ sc2out[tid] = sc; sc2out[128+tid] = sh; }
  }
  __syncthreads();
  const float inv24 = 1.f/24.f, f2324 = 23.f/24.f;
  for (int i=tid; i<96*16; i+=TB){
    int rl = i >> 4, c8 = (i & 15) << 3;
    int gn = row0 + rl;
    int b = gn / 24, n = gn - b*24;
    const bf16* base = h2 + (size_t)(b*NE + n*23)*NH + c8;
    float s[8] = {0,0,0,0,0,0,0,0};
    for (int e=0; e<23; ++e){
      b16x8 v = *(const b16x8*)(base + e*NH);
      #pragma unroll
      for (int j=0; j<8; ++j) s[j] += (float)v[j];
    }
    b16x8 o;
    #pragma unroll
    for (int j=0; j<8; ++j){
      int c = c8 + j;
      o[j] = (bf16)(scl[c]*s[j]*inv24 + shf[c]*f2324);
    }
    *(b16x8*)(As + rl*LDA + c8) = o;
  }
  int lane = tid & 63, w = tid >> 6;
  b16x8 bfr[4][2];
  load_bfrags(w31, 128, 0, bfr, lane, w);
  __syncthreads();
  f32x4 acc[6][2]; zero_acc(acc);
  gemm_regB(As, bfr, acc, lane);
  __syncthreads();
  epilogue_to_lds(acc, b1s, As, lane, w, 96);
  load_bfrags(w32, 128, 0, bfr, lane, w);
  __syncthreads();
  zero_acc(acc);
  gemm_regB(As, bfr, acc, lane);
  __syncthreads();
  epilogue_to_lds(acc, b2s, As, lane, w, 96);
  __syncthreads();
  store_and_stats(As, h3 + (size_t)row0*NH, bn3, tid, 96);
}

// ---- K5: per-edge MLP4: skip-GEMM + gather y4r/y4s, ELU, layer2 GEMM, ELU; block-local edge2node -> z4 + BN4 stats ----
__global__ __launch_bounds__(TB) void k5_edge2(const bf16* __restrict__ h2,
    const float* __restrict__ sc2, const float* __restrict__ y4r, const float* __restrict__ y4s,
    const float* __restrict__ w41, const float* __restrict__ b41,
    const float* __restrict__ w42, const float* __restrict__ b42,
    float* __restrict__ z4, float* __restrict__ bn4buck){
  __shared__ alignas(16) bf16 As[96*LDA];
  __shared__ float scl[128], shf[128], b1s[128], b2s[128];
  int tid = threadIdx.x;
  int b = blockIdx.x / 6, tile = blockIdx.x % 6;
  int e0 = tile * 92;
  if (tid < 128){ scl[tid]=sc2[tid]; shf[tid]=sc2[128+tid]; b1s[tid]=b41[tid]; b2s[tid]=b42[tid]; }
  __syncthreads();
  const bf16* h2b = h2 + (size_t)(b*NE + e0)*NH;
  for (int i=tid; i<96*16; i+=TB){
    int row = i >> 4, c8 = (i & 15) << 3;
    b16x8 o;
    if (row < 92){
      b16x8 v = *(const b16x8*)(h2b + (size_t)row*NH + c8);
      #pragma unroll
      for (int j=0; j<8; ++j) o[j] = (bf16)(scl[c8+j]*(float)v[j] + shf[c8+j]);
    } else {
      #pragma unroll
      for (int j=0; j<8; ++j) o[j] = (bf16)0.f;
    }
    *(b16x8*)(As + row*LDA + c8) = o;
  }
  int lane = tid & 63, w = tid >> 6;
  b16x8 bfr[4][2];
  load_bfrags(w41, 384, 256, bfr, lane, w);   // skip third of m4_w1
  __syncthreads();
  f32x4 acc[6][2]; zero_acc(acc);
  gemm_regB(As, bfr, acc, lane);
  __syncthreads();
  {
    int q = lane >> 4, n = lane & 15;
    const float* yrb = y4r + (size_t)b*NK*NH;
    const float* ysb = y4s + (size_t)b*NK*NH;
    #pragma unroll
    for (int mt=0; mt<6; ++mt)
      #pragma unroll
      for (int t=0; t<2; ++t){
        int col = (w*2+t)*16 + n;
        float bc = b1s[col];
        #pragma unroll
        for (int i=0; i<4; ++i){
          int rowl = mt*16 + q*4 + i;
          float v = 0.f;
          if (rowl < 92){
            int e = e0 + rowl;
            int r = e / 23;
            int j = e - r*23;
            int s = j + (j >= r);
            v = elu(acc[mt][t][i] + yrb[r*NH+col] + ysb[s*NH+col] + bc);
          }
          As[rowl*LDA + col] = (bf16)v;
        }
      }
  }
  load_bfrags(w42, 128, 0, bfr, lane, w);
  __syncthreads();
  zero_acc(acc);
  gemm_regB(As, bfr, acc, lane);
  __syncthreads();
  epilogue_to_lds(acc, b2s, As, lane, w, 92);
  __syncthreads();
  {
    int c = tid & 127, half = tid >> 7;
    float s = 0.f, s2 = 0.f;
    for (int row = half; row < 92; row += 2){
      float v = (float)As[row*LDA + c];
      s += v; s2 += v*v;
    }
    float* dst = bn4buck + (blockIdx.x & 31)*256;
    atomicAdd(&dst[c], s);
    atomicAdd(&dst[128+c], s2);
  }
  {
    int c = tid & 127, g0 = tid >> 7;
    for (int g = g0; g < 4; g += 2){
      float s = 0.f;
      for (int e=0; e<23; ++e) s += (float)As[(g*23+e)*LDA + c];
      z4[(size_t)(b*NK + tile*4 + g)*NH + c] = s;
    }
  }
}

// ---- K6: finalize BN4, apply affine to edge2node sums, final 3072->2 projection ----
__global__ __launch_bounds__(TB) void k6_out(const float* __restrict__ z4,
    const float* __restrict__ bn4buck, const float* __restrict__ g4, const float* __restrict__ be4,
    const float* __restrict__ fo_w, const float* __restrict__ fo_b, float* __restrict__ out){
  __shared__ float red[512];
  __shared__ float scl[128], shf[128];
  int tid = threadIdx.x, b = blockIdx.x;
  {
    int c = tid & 127, part = tid >> 7;
    float s = 0.f;
    for (int i=0; i<32; ++i) s += bn4buck[i*256 + part*128 + c];
    red[tid] = s;
  }
  __syncthreads();
  if (tid < 128){
    float mean = red[tid] / (float)BEcnt;
    float var  = red[128+tid] / (float)BEcnt - mean*mean;
    float rs = rsqrtf(var + EPS);
    float sc = g4[tid] * rs;
    scl[tid] = sc; shf[tid] = be4[tid] - mean*sc;
  }
  __syncthreads();
  const float inv24 = 1.f/24.f, f2324 = 23.f/24.f;
  float a0 = 0.f, a1 = 0.f;
  for (int i=tid; i<3072; i+=TB){
    int c = i & 127;
    float x = scl[c]*z4[(size_t)b*3072 + i]*inv24 + shf[c]*f2324;
    a0 += x * fo_w[i];
    a1 += x * fo_w[3072 + i];
  }
  red[tid] = a0; red[256+tid] = a1;
  __syncthreads();
  for (int st=128; st>0; st>>=1){
    if (tid < st){ red[tid] += red[tid+st]; red[256+tid] += red[256+tid+st]; }
    __syncthreads();
  }
  if (tid == 0){
    out[b*2+0] = red[0] + fo_b[0];
    out[b*2+1] = red[256] + fo_b[1];
  }
}

extern "C" void kernel_launch(void* const* d_in, const int* in_sizes, int n_in,
                              void* d_out, int out_size, void* d_ws, size_t ws_size,
                              hipStream_t stream){
  (void)in_sizes; (void)n_in; (void)out_size; (void)ws_size;
  const float* inputs = (const float*)d_in[0];
  const float* fo_w  = (const float*)d_in[3];
  const float* fo_b  = (const float*)d_in[4];
  const float* m1_w1=(const float*)d_in[5];  const float* m1_b1=(const float*)d_in[6];
  const float* m1_w2=(const float*)d_in[7];  const float* m1_b2=(const float*)d_in[8];
  const float* m1_g =(const float*)d_in[9];  const float* m1_be=(const float*)d_in[10];
  const float* m2_w1=(const float*)d_in[11]; const float* m2_b1=(const float*)d_in[12];
  const float* m2_w2=(const float*)d_in[13]; const float* m2_b2=(const float*)d_in[14];
  const float* m2_g =(const float*)d_in[15]; const float* m2_be=(const float*)d_in[16];
  const float* m3_w1=(const float*)d_in[17]; const float* m3_b1=(const float*)d_in[18];
  const float* m3_w2=(const float*)d_in[19]; const float* m3_b2=(const float*)d_in[20];
  const float* m3_g =(const float*)d_in[21]; const float* m3_be=(const float*)d_in[22];
  const float* m4_w1=(const float*)d_in[23]; const float* m4_b1=(const float*)d_in[24];
  const float* m4_w2=(const float*)d_in[25]; const float* m4_b2=(const float*)d_in[26];
  const float* m4_g =(const float*)d_in[27]; const float* m4_be=(const float*)d_in[28];

  char* ws = (char*)d_ws;
  float* stats = (float*)ws;
  bf16* h1  = (bf16*)(ws + OFF_H1);
  bf16* h3  = (bf16*)(ws + OFF_H3);
  float* y2r = (float*)(ws + OFF_Y2R);
  float* y2s = (float*)(ws + OFF_Y2S);
  float* y4r = (float*)(ws + OFF_Y4R);
  float* y4s = (float*)(ws + OFF_Y4S);
  float* z4  = (float*)(ws + OFF_Z4);
  bf16* h2  = (bf16*)(ws + OFF_H2);
  float* out = (float*)d_out;

  (void)hipMemsetAsync(d_ws, 0, STATS_BYTES, stream);
  k1_mlp1<<<256, TB, 0, stream>>>(inputs, m1_w1, m1_b1, m1_w2, m1_b2, h1, stats + S_BN1);
  k_project<<<256, TB, 0, stream>>>(h1, stats + S_BN1, (float)BNODE, m1_g, m1_be, m2_w1, 256, y2r, y2s);
  k3_edge1<<<6144, TB, 0, stream>>>(y2r, y2s, m2_b1, m2_w2, m2_b2, h2, stats + S_B2);
  k4a_mlp3<<<256, TB, 0, stream>>>(h2, stats + S_B2, m2_g, m2_be, m3_w1, m3_b1, m3_w2, m3_b2,
                                   h3, stats + S_BN3, stats + S_SC2);
  k_project<<<256, TB, 0, stream>>>(h3, stats + S_BN3, (float)BNODE, m3_g, m3_be, m4_w1, 384, y4r, y4s);
  k5_edge2<<<6144, TB, 0, stream>>>(h2, stats + S_SC2, y4r, y4s, m4_w1, m4_b1, m4_w2, m4_b2,
                                    z4, stats + S_B4);
  k6_out<<<1024, TB, 0, stream>>>(z4, stats + S_B4, m4_g, m4_be, fo_w, fo_b, out);
}